// Round 6
// baseline (5161.501 us; speedup 1.0000x reference)
//
#include <hip/hip_runtime.h>
#include <cstdint>

#define B_SZ   2048
#define T_SZ   80
#define VOCABN 80
#define EMBN   8
#define HID    256
#define G4     1024
#define TILE   16
#define NBLK   (B_SZ / TILE)   // 128
#define NTHR   512
#define NCH    24              // chunks per step: 8 W1h + 16 W2
#define CHE    32768           // bf16 elems per 64KB chunk

typedef __bf16 bf16;
typedef __attribute__((ext_vector_type(8))) __bf16 bf16x8;
typedef __attribute__((ext_vector_type(4))) float  f32x4;

__device__ __forceinline__ float sigf(float x)   { return 1.0f / (1.0f + __expf(-x)); }
__device__ __forceinline__ float tanhf2(float x) { return 1.0f - 2.0f / (__expf(2.0f * x) + 1.0f); }

__device__ __forceinline__ unsigned short f2bf(float f) {
    union { float f; unsigned int u; } v; v.f = f;
    unsigned int u = v.u;
    return (unsigned short)((u + 0x7FFFu + ((u >> 16) & 1u)) >> 16);
}

// Swizzled h-tile (verified R1-R4): [16][256] bf16, 16B blocks rotated by 2*row.
#define HSWZ(row, col) ((row) * 256 + (((((col) >> 3) + 2 * (row)) & 31) << 3) + ((col) & 7))
// A-fragment read (verified): row=lc, k-elems lg*8..+8 of 32-slice k_
#define AFRAG(hptr, k_) (*(const bf16x8*)&(hptr)[lc * 256 + (((4 * (k_) + lg + 2 * lc) & 31) << 3)])

// ---------------- prep: 25 k-major weight slices ----------------
// wp: [k(25)][nt(64)][lane(64)][8] bf16. k 0..7: W1 h-rows (base EMBN);
// k 8..23: W2 rows 0..511; k 24: W1 x-rows 0..7 (lg==0), zero elsewhere.
__global__ void prep_w(const float* __restrict__ W1, const float* __restrict__ W2,
                       unsigned short* __restrict__ wp) {
    int idx = blockIdx.x * blockDim.x + threadIdx.x;
    if (idx >= 25 * 64 * 64) return;
    int lane = idx & 63, nt = (idx >> 6) & 63, k = idx >> 12;
    int scol = (nt << 4) + (lane & 15);
    int lg = lane >> 4;
#pragma unroll
    for (int e = 0; e < 8; ++e) {
        float val;
        if (k < 8)       val = W1[(EMBN + k * 32 + lg * 8 + e) * G4 + scol];
        else if (k < 24) val = W2[((k - 8) * 32 + lg * 8 + e) * G4 + scol];
        else             val = (lg == 0) ? W1[e * G4 + scol] : 0.0f;
        wp[idx * 8 + e] = f2bf(val);
    }
}

// ---------------- sync / pipeline primitives (m201 pattern) ----------------
#define WAITVM(N) do { asm volatile("s_waitcnt vmcnt(" #N ")" ::: "memory"); \
                       __builtin_amdgcn_sched_barrier(0); } while (0)
#define WAITLG    do { asm volatile("s_waitcnt lgkmcnt(0)" ::: "memory");    \
                       __builtin_amdgcn_sched_barrier(0); } while (0)
#define BAR       do { __builtin_amdgcn_s_barrier();                         \
                       __builtin_amdgcn_sched_barrier(0); } while (0)

// Stage one 64KB chunk (slice kk -> wbuf[bb]): 8 global_load_lds_dwordx4 per wave.
// LDS dest wave-uniform base (+lane*16 by HW); verified in R2 (absmax 0).
#define STAGE(kk, bb) do {                                                      \
    const bf16* gs_ = wp + (size_t)(kk) * CHE;                                  \
    _Pragma("unroll")                                                           \
    for (int j_ = 0; j_ < 8; ++j_) {                                            \
        const int f_ = j_ * 512 + wid * 64;                                     \
        __builtin_amdgcn_global_load_lds(                                       \
            (const __attribute__((address_space(1))) void*)(gs_ + (size_t)(f_ + lane) * 8), \
            (__attribute__((address_space(3))) void*)(&wbuf[bb][0] + (size_t)f_ * 8),       \
            16, 0, 0);                                                          \
    }                                                                           \
} while (0)

// Consume chunk c: wait resident, barrier, 8 frag ds_reads + MFMAs (+EXTRA),
// confirm reads done, barrier, stage chunk c+2 (slice (c+2)%24, buf (c+2)&1).
#define CHUNK(c, HSRC, KIDX, EXTRA) do {                                        \
    WAITVM(8); BAR;                                                             \
    {                                                                           \
        const bf16* wb_ = wbuf[(c) & 1];                                        \
        bf16x8 afr_ = AFRAG(HSRC, KIDX);                                        \
        _Pragma("unroll")                                                       \
        for (int j_ = 0; j_ < 8; ++j_) {                                        \
            const int nt_ = (j_ >> 1) * 16 + 2 * wid + (j_ & 1);                \
            bf16x8 w_ = *(const bf16x8*)&wb_[(nt_ * 64 + lane) * 8];            \
            acc[j_ >> 1][j_ & 1] = __builtin_amdgcn_mfma_f32_16x16x32_bf16(     \
                afr_, w_, acc[j_ >> 1][j_ & 1], 0, 0, 0);                       \
        }                                                                       \
        EXTRA;                                                                  \
    }                                                                           \
    WAITLG; BAR;                                                                \
    STAGE(((c) + 2) % NCH, ((c) + 2) & 1);                                      \
} while (0)

// x-contribution for layer 1: one K=32 MFMA per tile, A = emb[token] (k=0..7).
#define XMFMA do {                                                              \
    const int tok_ = toks[lc * T_SZ + t];                                       \
    bf16x8 ax_;                                                                 \
    if (lg == 0) ax_ = *(const bf16x8*)&embL[tok_ * 8];                         \
    else { _Pragma("unroll") for (int e_ = 0; e_ < 8; ++e_) ax_[e_] = (bf16)0.0f; } \
    _Pragma("unroll")                                                           \
    for (int j_ = 0; j_ < 8; ++j_)                                              \
        acc[j_ >> 1][j_ & 1] = __builtin_amdgcn_mfma_f32_16x16x32_bf16(         \
            ax_, w1x[j_], acc[j_ >> 1][j_ & 1], 0, 0, 0);                       \
} while (0)

#define ACCZ() do { _Pragma("unroll") for (int g_ = 0; g_ < 4; ++g_) {          \
    acc[g_][0] = zf; acc[g_][1] = zf; } } while (0)

__global__ __launch_bounds__(NTHR, 2)
void lstm_fused(const int* __restrict__ feat, const int* __restrict__ labels,
                const bf16* __restrict__ wp,
                const float* __restrict__ b1, const float* __restrict__ b2,
                const float* __restrict__ emb,
                const float* __restrict__ Wd, const float* __restrict__ bd,
                float* __restrict__ out)
{
    __shared__ __align__(16) bf16  wbuf[2][CHE];          // 128 KB weight chunks
    __shared__ __align__(16) bf16  h1s[TILE * 256];       // 8 KB
    __shared__ __align__(16) bf16  h2s[TILE * 256];       // 8 KB
    __shared__ __align__(16) bf16  embL[VOCABN * 8];      // 1.25 KB
    __shared__ int   toks[TILE * T_SZ];                   // 5 KB
    __shared__ float logitb[TILE][VOCABN + 1];            // 5.1 KB
    __shared__ float lossb[TILE];

    const int tid  = threadIdx.x;
    const int lane = tid & 63;
    const int wid  = tid >> 6;
    const int lc   = lane & 15;
    const int lg   = lane >> 4;
    const int b0   = blockIdx.x * TILE;

    for (int i = tid; i < TILE * 256; i += NTHR) { h1s[i] = (bf16)0.0f; h2s[i] = (bf16)0.0f; }
    for (int i = tid; i < TILE * T_SZ; i += NTHR) {
        int r = i / T_SZ, t = i - r * T_SZ;
        toks[r * T_SZ + t] = feat[(b0 + r) * T_SZ + t];
    }
    for (int i = tid; i < VOCABN * 8; i += NTHR) embL[i] = *(bf16*)&(unsigned short&)(*(unsigned short[1]){f2bf(emb[i])});
    __syncthreads();

    // persistent W1x fragments (slice 24) + biases
    bf16x8 w1x[8];
#pragma unroll
    for (int j = 0; j < 8; ++j) {
        const int nt = (j >> 1) * 16 + 2 * wid + (j & 1);
        w1x[j] = *(const bf16x8*)&wp[((size_t)24 * 64 * 64 + nt * 64 + lane) * 8];
    }
    float b1v[4][2], b2v[4][2];
#pragma unroll
    for (int g = 0; g < 4; ++g)
#pragma unroll
        for (int d = 0; d < 2; ++d) {
            b1v[g][d] = b1[g * 256 + (2 * wid + d) * 16 + lc];
            b2v[g][d] = b2[g * 256 + (2 * wid + d) * 16 + lc];
        }

    const f32x4 zf = {0.f, 0.f, 0.f, 0.f};
    f32x4 acc[4][2];
    float c1s[2][4] = {{0.f,0.f,0.f,0.f},{0.f,0.f,0.f,0.f}};
    float c2s[2][4] = {{0.f,0.f,0.f,0.f},{0.f,0.f,0.f,0.f}};

    // prologue: two chunks in flight
    STAGE(0, 0);
    STAGE(1, 1);

    for (int t = 0; t < T_SZ; ++t) {
        // ---------- layer 1: chunks 0..7 (W1h), + x-MFMA ----------
        ACCZ();
        CHUNK(0, h1s, 0, XMFMA);
        CHUNK(1, h1s, 1, );
        CHUNK(2, h1s, 2, );
        CHUNK(3, h1s, 3, );
        CHUNK(4, h1s, 4, );
        CHUNK(5, h1s, 5, );
        CHUNK(6, h1s, 6, );
        CHUNK(7, h1s, 7, );
        // pointwise L1 -> h1s (all h1s reads happened in chunk bodies, confirmed)
#pragma unroll
        for (int d = 0; d < 2; ++d) {
            const int hcol = (2 * wid + d) * 16 + lc;
#pragma unroll
            for (int rr = 0; rr < 4; ++rr) {
                const int row = lg * 4 + rr;
                float gi = acc[0][d][rr] + b1v[0][d];
                float gj = acc[1][d][rr] + b1v[1][d];
                float gf = acc[2][d][rr] + b1v[2][d];
                float go = acc[3][d][rr] + b1v[3][d];
                float cn = c1s[d][rr] * sigf(gf + 1.0f) + sigf(gi) * tanhf2(gj);
                float h  = tanhf2(cn) * sigf(go);
                c1s[d][rr] = cn;
                h1s[HSWZ(row, hcol)] = (bf16)h;
            }
        }
        // ---------- layer 2: chunks 8..15 (x-part, fresh h1), 16..23 (h-part) ----------
        ACCZ();
        CHUNK(8,  h1s, 0, );
        CHUNK(9,  h1s, 1, );
        CHUNK(10, h1s, 2, );
        CHUNK(11, h1s, 3, );
        CHUNK(12, h1s, 4, );
        CHUNK(13, h1s, 5, );
        CHUNK(14, h1s, 6, );
        CHUNK(15, h1s, 7, );
        CHUNK(16, h2s, 0, );
        CHUNK(17, h2s, 1, );
        CHUNK(18, h2s, 2, );
        CHUNK(19, h2s, 3, );
        CHUNK(20, h2s, 4, );
        CHUNK(21, h2s, 5, );
        CHUNK(22, h2s, 6, );
        CHUNK(23, h2s, 7, );
        // pointwise L2 -> h2s
#pragma unroll
        for (int d = 0; d < 2; ++d) {
            const int hcol = (2 * wid + d) * 16 + lc;
#pragma unroll
            for (int rr = 0; rr < 4; ++rr) {
                const int row = lg * 4 + rr;
                float gi = acc[0][d][rr] + b2v[0][d];
                float gj = acc[1][d][rr] + b2v[1][d];
                float gf = acc[2][d][rr] + b2v[2][d];
                float go = acc[3][d][rr] + b2v[3][d];
                float cn = c2s[d][rr] * sigf(gf + 1.0f) + sigf(gi) * tanhf2(gj);
                float h  = tanhf2(cn) * sigf(go);
                c2s[d][rr] = cn;
                h2s[HSWZ(row, hcol)] = (bf16)h;
            }
        }
    }
    __syncthreads();   // loop done; drain + make h2s visible for epilogue

    // ---- epilogue: logits = h2_last @ Wd + bd, log-softmax NLL, mean ----
    for (int pp = tid; pp < TILE * VOCABN; pp += NTHR) {
        int row = pp / VOCABN, v = pp - row * VOCABN;
        float s = bd[v];
        for (int k = 0; k < HID; ++k)
            s += (float)h2s[HSWZ(row, k)] * Wd[k * VOCABN + v];
        logitb[row][v] = s;
    }
    __syncthreads();
    if (tid < TILE) {
        const int row = tid;
        float m = -1e30f;
        for (int v = 0; v < VOCABN; ++v) m = fmaxf(m, logitb[row][v]);
        float s = 0.f;
        for (int v = 0; v < VOCABN; ++v) s += __expf(logitb[row][v] - m);
        int lab = labels[b0 + row];
        lossb[row] = m + __logf(s) - logitb[row][lab];
    }
    __syncthreads();
    if (tid == 0) {
        float s = 0.f;
#pragma unroll
        for (int rr = 0; rr < TILE; ++rr) s += lossb[rr];
        atomicAdd(out, s * (1.0f / (float)B_SZ));
    }
}

extern "C" void kernel_launch(void* const* d_in, const int* in_sizes, int n_in,
                              void* d_out, int out_size, void* d_ws, size_t ws_size,
                              hipStream_t stream)
{
    (void)in_sizes; (void)n_in; (void)out_size; (void)ws_size;
    const int*   feat   = (const int*)d_in[0];
    const int*   labels = (const int*)d_in[1];
    const float* emb    = (const float*)d_in[2];
    const float* W1     = (const float*)d_in[3];
    const float* b1     = (const float*)d_in[4];
    const float* W2     = (const float*)d_in[5];
    const float* b2     = (const float*)d_in[6];
    const float* Wd     = (const float*)d_in[7];
    const float* bd     = (const float*)d_in[8];
    float* out = (float*)d_out;

    bf16* wp = (bf16*)d_ws;   // 25 * 64 * 64 * 8 * 2 = 1,638,400 B

    hipMemsetAsync(d_out, 0, sizeof(float), stream);
    prep_w<<<(25 * 64 * 64 + 255) / 256, 256, 0, stream>>>(W1, W2, (unsigned short*)wp);
    lstm_fused<<<NBLK, NTHR, 0, stream>>>(feat, labels, wp, b1, b2, emb, Wd, bd, out);
}

// Round 9
// 5149.318 us; speedup vs baseline: 1.0024x; 1.0024x over previous
//
#include <hip/hip_runtime.h>
#include <cstdint>

#define B_SZ   2048
#define T_SZ   80
#define VOCABN 80
#define EMBN   8
#define HID    256
#define G4     1024
#define NTHR   512

typedef __bf16 bf16;
typedef __attribute__((ext_vector_type(8))) __bf16 bf16x8;
typedef __attribute__((ext_vector_type(4))) float  f32x4;
typedef __attribute__((ext_vector_type(4))) unsigned short u16x4;

__device__ __forceinline__ float sigf(float x)   { return 1.0f / (1.0f + __expf(-x)); }
__device__ __forceinline__ float tanhf2(float x) { return 1.0f - 2.0f / (__expf(2.0f * x) + 1.0f); }

__device__ __forceinline__ unsigned short f2bf(float f) {
    union { float f; unsigned int u; } v; v.f = f;
    unsigned int u = v.u;
    return (unsigned short)((u + 0x7FFFu + ((u >> 16) & 1u)) >> 16);
}
__device__ __forceinline__ float bf2f(unsigned short h) {
    union { unsigned int u; float f; } v; v.u = ((unsigned int)h) << 16;
    return v.f;
}

// Swizzled h-tile (verified R1-R5): [16][256] bf16, 16B blocks rotated by 2*row.
#define HSWZ(row, col) ((row) * 256 + (((((col) >> 3) + 2 * (row)) & 31) << 3) + ((col) & 7))
// A-fragment read (verified): A-rows = lc, k-cols (k*32 + lg*8 .. +8)
#define AFRAG(hptr, k_) (*(const bf16x8*)&(hptr)[lc * 256 + (((4 * (k_) + lg + 2 * lc) & 31) << 3)])

// ===================== ws layout =====================
#define WPA_OFF  0ull                      // 512 KB  W1h  [k8][nt64][lane64][8]
#define WPG_OFF  524288ull                 // 512 KB  W2x
#define WPB_OFF  1048576ull                // 512 KB  W2h
#define W1X_OFF  1572864ull                // 64 KB   W1x K=32 frag (zeros for lg>0)
#define H1G_OFF  1638400ull                // 84 MB   h1[b*80+t][256] bf16
#define GX_OFF   85524480ull               // 336 MB  gx[bblk][t][nt][lc][rb] bf16
#define WS_NEED  421068800ull

// ===================== prep: gate-tile packed weights =====================
// nt = w*8 + hf*4 + g ; scol = g*256 + w*32 + hf*16 + lc
// wp[s][k][nt][lane][8] : value = SRC[rowbase + k*32 + lg*8 + e][scol]
__global__ void prep_all(const float* __restrict__ W1, const float* __restrict__ W2,
                         unsigned short* __restrict__ wpA, unsigned short* __restrict__ wpG,
                         unsigned short* __restrict__ wpB, unsigned short* __restrict__ w1xg) {
    int idx = blockIdx.x * blockDim.x + threadIdx.x;
    if (idx < 3 * 8 * 64 * 64) {
        int s = idx >> 15, rem = idx & 32767;
        int k = rem >> 12, nt = (rem >> 6) & 63, lane = rem & 63;
        int lc = lane & 15, lg = lane >> 4;
        int scol = (nt & 3) * 256 + (nt >> 3) * 32 + ((nt >> 2) & 1) * 16 + lc;
        unsigned short* dst = (s == 0) ? wpA : (s == 1 ? wpG : wpB);
#pragma unroll
        for (int e = 0; e < 8; ++e) {
            int row = k * 32 + lg * 8 + e;
            float val = (s == 0) ? W1[(EMBN + row) * G4 + scol]
                      : (s == 1) ? W2[row * G4 + scol]
                                 : W2[(256 + row) * G4 + scol];
            dst[rem * 8 + e] = f2bf(val);
        }
    } else if (idx < 3 * 8 * 64 * 64 + 64 * 64) {
        int i = idx - 3 * 8 * 64 * 64;
        int nt = i >> 6, lane = i & 63;
        int lc = lane & 15, lg = lane >> 4;
        int scol = (nt & 3) * 256 + (nt >> 3) * 32 + ((nt >> 2) & 1) * 16 + lc;
#pragma unroll
        for (int e = 0; e < 8; ++e)
            w1xg[i * 8 + e] = (lg == 0) ? f2bf(W1[e * G4 + scol]) : (unsigned short)0;
    }
}

// ===================== kernel A: layer-1 recurrence =====================
__global__ __launch_bounds__(NTHR, 2)
void lstm_l1(const int* __restrict__ feat,
             const bf16x8* __restrict__ wpA, const bf16x8* __restrict__ w1xg,
             const float* __restrict__ emb, const float* __restrict__ b1,
             unsigned short* __restrict__ h1g)
{
    __shared__ __align__(16) bf16 wlds[2 * 4096 * 8];     // 128 KB: slices k=6,7
    __shared__ __align__(16) bf16 h1s[2][16 * 256];       // 16 KB (rows 8..15 stay 0)
    __shared__ __align__(16) bf16 embl[VOCABN * 8];       // 1.25 KB
    __shared__ unsigned char toks8[8 * T_SZ];             // 640 B

    const int tid  = threadIdx.x;
    const int lane = tid & 63;
    const int wid  = tid >> 6;
    const int lc   = lane & 15;
    const int lg   = lane >> 4;
    const int bblk = blockIdx.x;
    const int b0   = bblk * 8;

    for (int i = tid; i < 2 * 16 * 256; i += NTHR) h1s[0][i] = (bf16)0.0f;
    for (int i = tid; i < VOCABN * 8; i += NTHR) ((unsigned short*)embl)[i] = f2bf(emb[i]);
    for (int i = tid; i < 8 * T_SZ; i += NTHR) {
        int r = i / T_SZ, t = i - r * T_SZ;
        toks8[i] = (unsigned char)feat[(b0 + r) * T_SZ + t];
    }
    {   // wlds <- wpA slices 6,7 (verbatim fragment order)
        bf16x8* wv = (bf16x8*)wlds;
        for (int i = tid; i < 2 * 4096; i += NTHR) wv[i] = wpA[6 * 4096 + i];
    }
    __syncthreads();

    // resident: 6 reg slices (k=0..5), this wave's 8 tiles each
    bf16x8 wreg[48];
#pragma unroll
    for (int k = 0; k < 6; ++k)
#pragma unroll
        for (int j = 0; j < 8; ++j)
            wreg[k * 8 + j] = wpA[(k * 64 + wid * 8 + j) * 64 + lane];

    float b1v[2][4];
#pragma unroll
    for (int hf = 0; hf < 2; ++hf)
#pragma unroll
        for (int g = 0; g < 4; ++g)
            b1v[hf][g] = b1[g * 256 + wid * 32 + hf * 16 + lc];

    const f32x4 zf = {0.f, 0.f, 0.f, 0.f};
    float c1[2][4] = {{0.f,0.f,0.f,0.f},{0.f,0.f,0.f,0.f}};
    const bf16x8* wldsv = (const bf16x8*)wlds;

    for (int t = 0; t < T_SZ; ++t) {
        const int rb_ = t & 1;
        const bf16* hr = h1s[rb_];
        bf16* hw = h1s[rb_ ^ 1];

        // emb A-fragment (rows=lc, cols=lg*8+e; real cols only lg==0)
        bf16x8 ax;
        for (int e = 0; e < 8; ++e) ax[e] = (bf16)0.0f;
        if (lg == 0) ax = *(const bf16x8*)&embl[(int)toks8[(lc & 7) * T_SZ + t] * 8];

#pragma unroll
        for (int hf = 0; hf < 2; ++hf) {
            f32x4 a4[4];
#pragma unroll
            for (int g = 0; g < 4; ++g) a4[g] = zf;
            // x-part: one K=32 MFMA per gate (w1xg has zeros for rows 8..31)
#pragma unroll
            for (int g = 0; g < 4; ++g) {
                bf16x8 xw = w1xg[(wid * 8 + hf * 4 + g) * 64 + lane];
                a4[g] = __builtin_amdgcn_mfma_f32_16x16x32_bf16(ax, xw, a4[g], 0, 0, 0);
            }
            // h-part: k=0..5 from registers
#pragma unroll
            for (int k = 0; k < 6; ++k) {
                bf16x8 afr = AFRAG(hr, k);
#pragma unroll
                for (int g = 0; g < 4; ++g)
                    a4[g] = __builtin_amdgcn_mfma_f32_16x16x32_bf16(afr, wreg[k * 8 + hf * 4 + g], a4[g], 0, 0, 0);
            }
            // k=6,7 from LDS
#pragma unroll
            for (int k = 6; k < 8; ++k) {
                bf16x8 afr = AFRAG(hr, k);
#pragma unroll
                for (int g = 0; g < 4; ++g) {
                    bf16x8 w = wldsv[((k - 6) * 64 + wid * 8 + hf * 4 + g) * 64 + lane];
                    a4[g] = __builtin_amdgcn_mfma_f32_16x16x32_bf16(afr, w, a4[g], 0, 0, 0);
                }
            }
            // pointwise (real rows 0..7 -> lg<2)
            if (lg < 2) {
                const int hcol = wid * 32 + hf * 16 + lc;
#pragma unroll
                for (int r = 0; r < 4; ++r) {
                    const int row = lg * 4 + r;
                    float gi = a4[0][r] + b1v[hf][0];
                    float gj = a4[1][r] + b1v[hf][1];
                    float gf = a4[2][r] + b1v[hf][2];
                    float go = a4[3][r] + b1v[hf][3];
                    float cn = c1[hf][r] * sigf(gf + 1.0f) + sigf(gi) * tanhf2(gj);
                    float h  = tanhf2(cn) * sigf(go);
                    c1[hf][r] = cn;
                    unsigned short hb = f2bf(h);
                    hw[HSWZ(row, hcol)] = *(bf16*)&hb;
                    h1g[((size_t)(b0 + row) * T_SZ + t) * 256 + hcol] = hb;
                }
            }
        }
        __syncthreads();
    }
}

// ===================== kernel G: gx = h1 @ W2x + b2 =====================
// gx[bblk][t][nt][lc][rb] bf16 ; M-tile = 8 rb x 2 t  (m = rb*2+dt)
__global__ __launch_bounds__(NTHR, 2)
void gx_gemm(const unsigned short* __restrict__ h1g, const bf16x8* __restrict__ wpG,
             const float* __restrict__ b2, unsigned short* __restrict__ gx)
{
    __shared__ __align__(16) bf16 wlds[2 * 4096 * 8];     // 128 KB
    __shared__ __align__(16) bf16 hbuf[16 * 256];         // 8 KB

    const int tid  = threadIdx.x;
    const int lane = tid & 63;
    const int wid  = tid >> 6;
    const int lc   = lane & 15;
    const int lg   = lane >> 4;
    const int bblk = blockIdx.x;

    {
        bf16x8* wv = (bf16x8*)wlds;
        for (int i = tid; i < 2 * 4096; i += NTHR) wv[i] = wpG[6 * 4096 + i];
    }
    bf16x8 wreg[48];
#pragma unroll
    for (int k = 0; k < 6; ++k)
#pragma unroll
        for (int j = 0; j < 8; ++j)
            wreg[k * 8 + j] = wpG[(k * 64 + wid * 8 + j) * 64 + lane];

    float b2v[8];
#pragma unroll
    for (int j = 0; j < 8; ++j)
        b2v[j] = b2[(j & 3) * 256 + wid * 32 + ((j >> 2) & 1) * 16 + lc];

    const f32x4 zf = {0.f, 0.f, 0.f, 0.f};
    const bf16x8* wldsv = (const bf16x8*)wlds;
    const int m    = tid >> 5;            // staging: LDS row 0..15
    const int col0 = (tid & 31) * 8;

    // prologue: stage Mt 0
    bf16x8 sreg = *(const bf16x8*)&h1g[((size_t)(bblk * 8 + (m >> 1)) * T_SZ + (m & 1)) * 256 + col0];

    for (int tt = 0; tt < 40; ++tt) {
        const int t0 = tt * 2;
        __syncthreads();                  // readers of previous hbuf done
        *(bf16x8*)&hbuf[m * 256 + ((((tid & 31) + 2 * m) & 31) << 3)] = sreg;
        __syncthreads();
        if (tt + 1 < 40)
            sreg = *(const bf16x8*)&h1g[((size_t)(bblk * 8 + (m >> 1)) * T_SZ + (tt + 1) * 2 + (m & 1)) * 256 + col0];

        f32x4 acc[8];
#pragma unroll
        for (int j = 0; j < 8; ++j) acc[j] = zf;
#pragma unroll
        for (int k = 0; k < 8; ++k) {
            bf16x8 afr = AFRAG(hbuf, k);
#pragma unroll
            for (int j = 0; j < 8; ++j) {
                bf16x8 w = (k < 6) ? wreg[k * 8 + j]
                                   : wldsv[((k - 6) * 64 + wid * 8 + j) * 64 + lane];
                acc[j] = __builtin_amdgcn_mfma_f32_16x16x32_bf16(afr, w, acc[j], 0, 0, 0);
            }
        }
        // store: C row = 4lg+r -> rb = 2lg + (r>>1), dt = r&1
#pragma unroll
        for (int j = 0; j < 8; ++j) {
            const int nt = wid * 8 + j;
#pragma unroll
            for (int r = 0; r < 4; ++r) {
                size_t addr = ((((size_t)bblk * T_SZ + t0 + (r & 1)) * 64 + nt) * 16 + lc) * 8
                              + 2 * lg + (r >> 1);
                gx[addr] = f2bf(acc[j][r] + b2v[j]);
            }
        }
    }
}

// ===================== kernel B: layer-2 recurrence + loss =====================
__global__ __launch_bounds__(NTHR, 2)
void lstm_l2(const bf16x8* __restrict__ wpB, const unsigned short* __restrict__ gx,
             const int* __restrict__ labels,
             const float* __restrict__ Wd, const float* __restrict__ bd,
             float* __restrict__ out)
{
    __shared__ __align__(16) bf16 wlds[2 * 4096 * 8];     // 128 KB
    __shared__ __align__(16) bf16 h2s[2][16 * 256];       // 16 KB
    __shared__ float logitb[8][VOCABN + 1];
    __shared__ float lossb[8];

    const int tid  = threadIdx.x;
    const int lane = tid & 63;
    const int wid  = tid >> 6;
    const int lc   = lane & 15;
    const int lg   = lane >> 4;
    const int bblk = blockIdx.x;

    for (int i = tid; i < 2 * 16 * 256; i += NTHR) h2s[0][i] = (bf16)0.0f;
    {
        bf16x8* wv = (bf16x8*)wlds;
        for (int i = tid; i < 2 * 4096; i += NTHR) wv[i] = wpB[6 * 4096 + i];
    }
    __syncthreads();

    bf16x8 wreg[48];
#pragma unroll
    for (int k = 0; k < 6; ++k)
#pragma unroll
        for (int j = 0; j < 8; ++j)
            wreg[k * 8 + j] = wpB[(k * 64 + wid * 8 + j) * 64 + lane];

    const f32x4 zf = {0.f, 0.f, 0.f, 0.f};
    float c2[2][4] = {{0.f,0.f,0.f,0.f},{0.f,0.f,0.f,0.f}};
    const bf16x8* wldsv = (const bf16x8*)wlds;

    for (int t = 0; t < T_SZ; ++t) {
        const int rb_ = t & 1;
        const bf16* hr = h2s[rb_];
        bf16* hw = h2s[rb_ ^ 1];

        // prefetch this step's gx (only real-row lanes)
        u16x4 gxv[2][4];
        if (lg < 2) {
#pragma unroll
            for (int hf = 0; hf < 2; ++hf)
#pragma unroll
                for (int g = 0; g < 4; ++g) {
                    const int nt = wid * 8 + hf * 4 + g;
                    size_t addr = ((((size_t)bblk * T_SZ + t) * 64 + nt) * 16 + lc) * 8 + 4 * lg;
                    gxv[hf][g] = *(const u16x4*)(gx + addr);
                }
        }

#pragma unroll
        for (int hf = 0; hf < 2; ++hf) {
            f32x4 a4[4];
#pragma unroll
            for (int g = 0; g < 4; ++g) a4[g] = zf;
#pragma unroll
            for (int k = 0; k < 6; ++k) {
                bf16x8 afr = AFRAG(hr, k);
#pragma unroll
                for (int g = 0; g < 4; ++g)
                    a4[g] = __builtin_amdgcn_mfma_f32_16x16x32_bf16(afr, wreg[k * 8 + hf * 4 + g], a4[g], 0, 0, 0);
            }
#pragma unroll
            for (int k = 6; k < 8; ++k) {
                bf16x8 afr = AFRAG(hr, k);
#pragma unroll
                for (int g = 0; g < 4; ++g) {
                    bf16x8 w = wldsv[((k - 6) * 64 + wid * 8 + hf * 4 + g) * 64 + lane];
                    a4[g] = __builtin_amdgcn_mfma_f32_16x16x32_bf16(afr, w, a4[g], 0, 0, 0);
                }
            }
            if (lg < 2) {
                const int hcol = wid * 32 + hf * 16 + lc;
#pragma unroll
                for (int r = 0; r < 4; ++r) {
                    const int row = lg * 4 + r;
                    float gi = a4[0][r] + bf2f(gxv[hf][0][r]);
                    float gj = a4[1][r] + bf2f(gxv[hf][1][r]);
                    float gf = a4[2][r] + bf2f(gxv[hf][2][r]);
                    float go = a4[3][r] + bf2f(gxv[hf][3][r]);
                    float cn = c2[hf][r] * sigf(gf + 1.0f) + sigf(gi) * tanhf2(gj);
                    float h  = tanhf2(cn) * sigf(go);
                    c2[hf][r] = cn;
                    unsigned short hb = f2bf(h);
                    hw[HSWZ(row, hcol)] = *(bf16*)&hb;
                }
            }
        }
        __syncthreads();
    }

    // ---- loss epilogue: final h2 in h2s[0] (t=79 wrote buf 0) ----
    const bf16* h2fin = h2s[0];
    for (int pp = tid; pp < 8 * VOCABN; pp += NTHR) {
        int row = pp / VOCABN, v = pp - row * VOCABN;
        float s = bd[v];
        for (int k = 0; k < HID; ++k)
            s += (float)h2fin[HSWZ(row, k)] * Wd[k * VOCABN + v];
        logitb[row][v] = s;
    }
    __syncthreads();
    if (tid < 8) {
        float mx = -1e30f;
        for (int v = 0; v < VOCABN; ++v) mx = fmaxf(mx, logitb[tid][v]);
        float s = 0.f;
        for (int v = 0; v < VOCABN; ++v) s += __expf(logitb[tid][v] - mx);
        int lab = labels[bblk * 8 + tid];
        lossb[tid] = mx + __logf(s) - logitb[tid][lab];
    }
    __syncthreads();
    if (tid == 0) {
        float s = 0.f;
#pragma unroll
        for (int r = 0; r < 8; ++r) s += lossb[r];
        atomicAdd(out, s * (1.0f / (float)B_SZ));
    }
}

// ===================== R5 fallback (verbatim, passed @5.16ms) =====================
#define NCH_R5 24
#define CHE_R5 32768
#define TILE_R5 16
#define NBLK_R5 (B_SZ / TILE_R5)

__global__ void prep_w_r5(const float* __restrict__ W1, const float* __restrict__ W2,
                          unsigned short* __restrict__ wp) {
    int idx = blockIdx.x * blockDim.x + threadIdx.x;
    if (idx >= 25 * 64 * 64) return;
    int lane = idx & 63, nt = (idx >> 6) & 63, k = idx >> 12;
    int scol = (nt << 4) + (lane & 15);
    int lg = lane >> 4;
#pragma unroll
    for (int e = 0; e < 8; ++e) {
        float val;
        if (k < 8)       val = W1[(EMBN + k * 32 + lg * 8 + e) * G4 + scol];
        else if (k < 24) val = W2[((k - 8) * 32 + lg * 8 + e) * G4 + scol];
        else             val = (lg == 0) ? W1[e * G4 + scol] : 0.0f;
        wp[idx * 8 + e] = f2bf(val);
    }
}

#define WAITVM_R5(N) do { asm volatile("s_waitcnt vmcnt(" #N ")" ::: "memory"); \
                       __builtin_amdgcn_sched_barrier(0); } while (0)
#define WAITLG_R5    do { asm volatile("s_waitcnt lgkmcnt(0)" ::: "memory");    \
                       __builtin_amdgcn_sched_barrier(0); } while (0)
#define BAR_R5       do { __builtin_amdgcn_s_barrier();                         \
                       __builtin_amdgcn_sched_barrier(0); } while (0)

#define STAGE_R5(kk, bb) do {                                                   \
    const bf16* gs_ = wp + (size_t)(kk) * CHE_R5;                               \
    _Pragma("unroll")                                                           \
    for (int j_ = 0; j_ < 8; ++j_) {                                            \
        const int f_ = j_ * 512 + wid * 64;                                     \
        __builtin_amdgcn_global_load_lds(                                       \
            (const __attribute__((address_space(1))) void*)(gs_ + (size_t)(f_ + lane) * 8), \
            (__attribute__((address_space(3))) void*)(&wbuf[bb][0] + (size_t)f_ * 8),       \
            16, 0, 0);                                                          \
    }                                                                           \
} while (0)

#define CHUNK_R5(c, HSRC, KIDX, EXTRA) do {                                     \
    WAITVM_R5(8); BAR_R5;                                                       \
    {                                                                           \
        const bf16* wb_ = wbuf[(c) & 1];                                        \
        bf16x8 afr_ = AFRAG(HSRC, KIDX);                                        \
        _Pragma("unroll")                                                       \
        for (int j_ = 0; j_ < 8; ++j_) {                                        \
            const int nt_ = (j_ >> 1) * 16 + 2 * wid + (j_ & 1);                \
            bf16x8 w_ = *(const bf16x8*)&wb_[(nt_ * 64 + lane) * 8];            \
            acc[j_ >> 1][j_ & 1] = __builtin_amdgcn_mfma_f32_16x16x32_bf16(     \
                afr_, w_, acc[j_ >> 1][j_ & 1], 0, 0, 0);                       \
        }                                                                       \
        EXTRA;                                                                  \
    }                                                                           \
    WAITLG_R5; BAR_R5;                                                          \
    STAGE_R5(((c) + 2) % NCH_R5, ((c) + 2) & 1);                                \
} while (0)

#define XMFMA_R5 do {                                                           \
    const int tok_ = toks[lc * T_SZ + t];                                       \
    bf16x8 ax_;                                                                 \
    _Pragma("unroll") for (int e_ = 0; e_ < 8; ++e_) ax_[e_] = (bf16)0.0f;      \
    if (lg == 0) ax_ = *(const bf16x8*)&embL[tok_ * 8];                         \
    _Pragma("unroll")                                                           \
    for (int j_ = 0; j_ < 8; ++j_)                                              \
        acc[j_ >> 1][j_ & 1] = __builtin_amdgcn_mfma_f32_16x16x32_bf16(         \
            ax_, w1x[j_], acc[j_ >> 1][j_ & 1], 0, 0, 0);                       \
} while (0)

#define ACCZ_R5() do { _Pragma("unroll") for (int g_ = 0; g_ < 4; ++g_) {       \
    acc[g_][0] = zf; acc[g_][1] = zf; } } while (0)

__global__ __launch_bounds__(NTHR, 2)
void lstm_fused_r5(const int* __restrict__ feat, const int* __restrict__ labels,
                const bf16* __restrict__ wp,
                const float* __restrict__ b1, const float* __restrict__ b2,
                const float* __restrict__ emb,
                const float* __restrict__ Wd, const float* __restrict__ bd,
                float* __restrict__ out)
{
    __shared__ __align__(16) bf16  wbuf[2][CHE_R5];
    __shared__ __align__(16) bf16  h1s[TILE_R5 * 256];
    __shared__ __align__(16) bf16  h2s[TILE_R5 * 256];
    __shared__ __align__(16) bf16  embL[VOCABN * 8];
    __shared__ int   toks[TILE_R5 * T_SZ];
    __shared__ float logitb[TILE_R5][VOCABN + 1];
    __shared__ float lossb[TILE_R5];

    const int tid  = threadIdx.x;
    const int lane = tid & 63;
    const int wid  = tid >> 6;
    const int lc   = lane & 15;
    const int lg   = lane >> 4;
    const int b0   = blockIdx.x * TILE_R5;

    for (int i = tid; i < TILE_R5 * 256; i += NTHR) { h1s[i] = (bf16)0.0f; h2s[i] = (bf16)0.0f; }
    for (int i = tid; i < TILE_R5 * T_SZ; i += NTHR) {
        int r = i / T_SZ, t = i - r * T_SZ;
        toks[r * T_SZ + t] = feat[(b0 + r) * T_SZ + t];
    }
    for (int i = tid; i < VOCABN * 8; i += NTHR) ((unsigned short*)embL)[i] = f2bf(emb[i]);
    __syncthreads();

    bf16x8 w1x[8];
#pragma unroll
    for (int j = 0; j < 8; ++j) {
        const int nt = (j >> 1) * 16 + 2 * wid + (j & 1);
        w1x[j] = *(const bf16x8*)&wp[((size_t)24 * 64 * 64 + nt * 64 + lane) * 8];
    }
    float b1v[4][2], b2v[4][2];
#pragma unroll
    for (int g = 0; g < 4; ++g)
#pragma unroll
        for (int d = 0; d < 2; ++d) {
            b1v[g][d] = b1[g * 256 + (2 * wid + d) * 16 + lc];
            b2v[g][d] = b2[g * 256 + (2 * wid + d) * 16 + lc];
        }

    const f32x4 zf = {0.f, 0.f, 0.f, 0.f};
    f32x4 acc[4][2];
    float c1s[2][4] = {{0.f,0.f,0.f,0.f},{0.f,0.f,0.f,0.f}};
    float c2s[2][4] = {{0.f,0.f,0.f,0.f},{0.f,0.f,0.f,0.f}};

    STAGE_R5(0, 0);
    STAGE_R5(1, 1);

    for (int t = 0; t < T_SZ; ++t) {
        ACCZ_R5();
        CHUNK_R5(0, h1s, 0, XMFMA_R5);
        CHUNK_R5(1, h1s, 1, );
        CHUNK_R5(2, h1s, 2, );
        CHUNK_R5(3, h1s, 3, );
        CHUNK_R5(4, h1s, 4, );
        CHUNK_R5(5, h1s, 5, );
        CHUNK_R5(6, h1s, 6, );
        CHUNK_R5(7, h1s, 7, );
#pragma unroll
        for (int d = 0; d < 2; ++d) {
            const int hcol = (2 * wid + d) * 16 + lc;
#pragma unroll
            for (int rr = 0; rr < 4; ++rr) {
                const int row = lg * 4 + rr;
                float gi = acc[0][d][rr] + b1v[0][d];
                float gj = acc[1][d][rr] + b1v[1][d];
                float gf = acc[2][d][rr] + b1v[2][d];
                float go = acc[3][d][rr] + b1v[3][d];
                float cn = c1s[d][rr] * sigf(gf + 1.0f) + sigf(gi) * tanhf2(gj);
                float h  = tanhf2(cn) * sigf(go);
                c1s[d][rr] = cn;
                h1s[HSWZ(row, hcol)] = (bf16)h;
            }
        }
        ACCZ_R5();
        CHUNK_R5(8,  h1s, 0, );
        CHUNK_R5(9,  h1s, 1, );
        CHUNK_R5(10, h1s, 2, );
        CHUNK_R5(11, h1s, 3, );
        CHUNK_R5(12, h1s, 4, );
        CHUNK_R5(13, h1s, 5, );
        CHUNK_R5(14, h1s, 6, );
        CHUNK_R5(15, h1s, 7, );
        CHUNK_R5(16, h2s, 0, );
        CHUNK_R5(17, h2s, 1, );
        CHUNK_R5(18, h2s, 2, );
        CHUNK_R5(19, h2s, 3, );
        CHUNK_R5(20, h2s, 4, );
        CHUNK_R5(21, h2s, 5, );
        CHUNK_R5(22, h2s, 6, );
        CHUNK_R5(23, h2s, 7, );
#pragma unroll
        for (int d = 0; d < 2; ++d) {
            const int hcol = (2 * wid + d) * 16 + lc;
#pragma unroll
            for (int rr = 0; rr < 4; ++rr) {
                const int row = lg * 4 + rr;
                float gi = acc[0][d][rr] + b2v[0][d];
                float gj = acc[1][d][rr] + b2v[1][d];
                float gf = acc[2][d][rr] + b2v[2][d];
                float go = acc[3][d][rr] + b2v[3][d];
                float cn = c2s[d][rr] * sigf(gf + 1.0f) + sigf(gi) * tanhf2(gj);
                float h  = tanhf2(cn) * sigf(go);
                c2s[d][rr] = cn;
                h2s[HSWZ(row, hcol)] = (bf16)h;
            }
        }
    }
    __syncthreads();

    for (int pp = tid; pp < TILE_R5 * VOCABN; pp += NTHR) {
        int row = pp / VOCABN, v = pp - row * VOCABN;
        float s = bd[v];
        for (int k = 0; k < HID; ++k)
            s += (float)h2s[HSWZ(row, k)] * Wd[k * VOCABN + v];
        logitb[row][v] = s;
    }
    __syncthreads();
    if (tid < TILE_R5) {
        const int row = tid;
        float m = -1e30f;
        for (int v = 0; v < VOCABN; ++v) m = fmaxf(m, logitb[row][v]);
        float s = 0.f;
        for (int v = 0; v < VOCABN; ++v) s += __expf(logitb[row][v] - m);
        int lab = labels[b0 + row];
        lossb[row] = m + __logf(s) - logitb[row][lab];
    }
    __syncthreads();
    if (tid == 0) {
        float s = 0.f;
#pragma unroll
        for (int rr = 0; rr < TILE_R5; ++rr) s += lossb[rr];
        atomicAdd(out, s * (1.0f / (float)B_SZ));
    }
}

// ===================== launch =====================
extern "C" void kernel_launch(void* const* d_in, const int* in_sizes, int n_in,
                              void* d_out, int out_size, void* d_ws, size_t ws_size,
                              hipStream_t stream)
{
    (void)in_sizes; (void)n_in; (void)out_size;
    const int*   feat   = (const int*)d_in[0];
    const int*   labels = (const int*)d_in[1];
    const float* emb    = (const float*)d_in[2];
    const float* W1     = (const float*)d_in[3];
    const float* b1     = (const float*)d_in[4];
    const float* W2     = (const float*)d_in[5];
    const float* b2     = (const float*)d_in[6];
    const float* Wd     = (const float*)d_in[7];
    const float* bd     = (const float*)d_in[8];
    float* out = (float*)d_out;
    char* ws = (char*)d_ws;

    (void)hipMemsetAsync(d_out, 0, sizeof(float), stream);

    if (ws_size >= WS_NEED) {
        unsigned short* wpA  = (unsigned short*)(ws + WPA_OFF);
        unsigned short* wpG  = (unsigned short*)(ws + WPG_OFF);
        unsigned short* wpB  = (unsigned short*)(ws + WPB_OFF);
        unsigned short* w1xg = (unsigned short*)(ws + W1X_OFF);
        unsigned short* h1g  = (unsigned short*)(ws + H1G_OFF);
        unsigned short* gx   = (unsigned short*)(ws + GX_OFF);

        prep_all<<<(3 * 8 * 64 * 64 + 64 * 64 + 255) / 256, 256, 0, stream>>>(
            W1, W2, wpA, wpG, wpB, w1xg);
        lstm_l1<<<256, NTHR, 0, stream>>>(feat, (const bf16x8*)wpA, (const bf16x8*)w1xg,
                                          emb, b1, h1g);
        gx_gemm<<<256, NTHR, 0, stream>>>(h1g, (const bf16x8*)wpG, b2, gx);
        lstm_l2<<<256, NTHR, 0, stream>>>((const bf16x8*)wpB, gx, labels, Wd, bd, out);
    } else {
        bf16* wp = (bf16*)d_ws;
        prep_w_r5<<<(25 * 64 * 64 + 255) / 256, 256, 0, stream>>>(W1, W2, (unsigned short*)wp);
        lstm_fused_r5<<<NBLK_R5, NTHR, 0, stream>>>(feat, labels, wp, b1, b2, emb, Wd, bd, out);
    }
}

// Round 10
// 1996.379 us; speedup vs baseline: 2.5854x; 2.5793x over previous
//
#include <hip/hip_runtime.h>
#include <cstdint>

#define B_SZ   2048
#define T_SZ   80
#define VOCABN 80
#define EMBN   8
#define HID    256
#define G4     1024
#define NTHR   512

typedef __bf16 bf16;
typedef __attribute__((ext_vector_type(8))) __bf16 bf16x8;
typedef __attribute__((ext_vector_type(4))) float  f32x4;
typedef __attribute__((ext_vector_type(4))) unsigned short u16x4;

__device__ __forceinline__ float sigf(float x)   { return 1.0f / (1.0f + __expf(-x)); }
__device__ __forceinline__ float tanhf2(float x) { return 1.0f - 2.0f / (__expf(2.0f * x) + 1.0f); }

__device__ __forceinline__ unsigned short f2bf(float f) {
    union { float f; unsigned int u; } v; v.f = f;
    unsigned int u = v.u;
    return (unsigned short)((u + 0x7FFFu + ((u >> 16) & 1u)) >> 16);
}
__device__ __forceinline__ float bf2f(unsigned short h) {
    union { unsigned int u; float f; } v; v.u = ((unsigned int)h) << 16;
    return v.f;
}

// Swizzled h-tile (verified R1-R5): [16][256] bf16, 16B blocks rotated by 2*row.
#define HSWZ(row, col) ((row) * 256 + (((((col) >> 3) + 2 * (row)) & 31) << 3) + ((col) & 7))
// A-fragment read (verified): A-rows = lc, k-cols (k*32 + lg*8 .. +8)
#define AFRAG(hptr, k_) (*(const bf16x8*)&(hptr)[lc * 256 + (((4 * (k_) + lg + 2 * lc) & 31) << 3)])

// ===================== ws layout (main path) =====================
#define WPA_OFF  0ull                      // 512 KB  W1h  [k8][nt64][lane64][8]
#define WPG_OFF  524288ull                 // 512 KB  W2x
#define WPB_OFF  1048576ull                // 512 KB  W2h
#define W1X_OFF  1572864ull                // 64 KB   W1x K=32 frag (zeros for lg>0)
#define C1G_OFF  1638400ull                // 2 MB    c1 state f32 [2048][256]
#define C2G_OFF  3735552ull                // 2 MB    c2 state f32
#define H2P_OFF  5832704ull                // 1 MB    h2 state bf16 [2048][256]
#define H1C_OFF  6881280ull                // TC*1MB  h1c [b][dt][256] bf16
#define FIXED_WS 6881280ull
#define PER_TC   5242880ull                // 1MB h1c + 4MB gxc per t

// ===================== prep: gate-tile packed weights =====================
// nt = w*8 + hf*4 + g ; scol = g*256 + w*32 + hf*16 + lc
__global__ void prep_all(const float* __restrict__ W1, const float* __restrict__ W2,
                         unsigned short* __restrict__ wpA, unsigned short* __restrict__ wpG,
                         unsigned short* __restrict__ wpB, unsigned short* __restrict__ w1xg) {
    int idx = blockIdx.x * blockDim.x + threadIdx.x;
    if (idx < 3 * 8 * 64 * 64) {
        int s = idx >> 15, rem = idx & 32767;
        int k = rem >> 12, nt = (rem >> 6) & 63, lane = rem & 63;
        int lc = lane & 15, lg = lane >> 4;
        int scol = (nt & 3) * 256 + (nt >> 3) * 32 + ((nt >> 2) & 1) * 16 + lc;
        unsigned short* dst = (s == 0) ? wpA : (s == 1 ? wpG : wpB);
#pragma unroll
        for (int e = 0; e < 8; ++e) {
            int row = k * 32 + lg * 8 + e;
            float val = (s == 0) ? W1[(EMBN + row) * G4 + scol]
                      : (s == 1) ? W2[row * G4 + scol]
                                 : W2[(256 + row) * G4 + scol];
            dst[rem * 8 + e] = f2bf(val);
        }
    } else if (idx < 3 * 8 * 64 * 64 + 64 * 64) {
        int i = idx - 3 * 8 * 64 * 64;
        int nt = i >> 6, lane = i & 63;
        int lc = lane & 15, lg = lane >> 4;
        int scol = (nt & 3) * 256 + (nt >> 3) * 32 + ((nt >> 2) & 1) * 16 + lc;
#pragma unroll
        for (int e = 0; e < 8; ++e)
            w1xg[i * 8 + e] = (lg == 0) ? f2bf(W1[e * G4 + scol]) : (unsigned short)0;
    }
}

// ===================== kernel A: layer-1 recurrence (time chunk) =====================
__global__ __launch_bounds__(NTHR, 2)
void lstm_l1(const int* __restrict__ feat,
             const bf16x8* __restrict__ wpA, const bf16x8* __restrict__ w1xg,
             const float* __restrict__ emb, const float* __restrict__ b1,
             unsigned short* __restrict__ h1c, float* __restrict__ c1g,
             int t0, int TC)
{
    __shared__ __align__(16) bf16 wlds[2 * 4096 * 8];     // 128 KB: slices k=6,7
    __shared__ __align__(16) bf16 h1s[2][16 * 256];       // 16 KB (rows 8..15 stay 0)
    __shared__ __align__(16) bf16 embl[VOCABN * 8];
    __shared__ unsigned char toks8[8 * T_SZ];

    const int tid  = threadIdx.x;
    const int lane = tid & 63;
    const int wid  = tid >> 6;
    const int lc   = lane & 15;
    const int lg   = lane >> 4;
    const int bblk = blockIdx.x;
    const int b0   = bblk * 8;
    const int t1   = t0 + TC;

    for (int i = tid; i < 2 * 16 * 256; i += NTHR) h1s[0][i] = (bf16)0.0f;
    for (int i = tid; i < VOCABN * 8; i += NTHR) ((unsigned short*)embl)[i] = f2bf(emb[i]);
    for (int i = tid; i < 8 * T_SZ; i += NTHR) {
        int r = i / T_SZ, t = i - r * T_SZ;
        toks8[i] = (unsigned char)feat[(b0 + r) * T_SZ + t];
    }
    {
        bf16x8* wv = (bf16x8*)wlds;
        for (int i = tid; i < 2 * 4096; i += NTHR) wv[i] = wpA[6 * 4096 + i];
    }
    float c1[2][4] = {{0.f,0.f,0.f,0.f},{0.f,0.f,0.f,0.f}};
    if (t0 > 0) {
        __syncthreads();   // zero-fill done before h_prev overwrite
        for (int i = tid; i < 256; i += NTHR) {            // 8 rows x 32 vec8
            int row = i >> 5, col0 = (i & 31) << 3;
            bf16x8 v = *(const bf16x8*)&h1c[((size_t)(b0 + row) * TC + (TC - 1)) * 256 + col0];
            *(bf16x8*)&h1s[0][HSWZ(row, col0)] = v;
        }
        if (lg < 2) {
#pragma unroll
            for (int hf = 0; hf < 2; ++hf)
#pragma unroll
                for (int r = 0; r < 4; ++r)
                    c1[hf][r] = c1g[(size_t)(b0 + lg * 4 + r) * 256 + wid * 32 + hf * 16 + lc];
        }
    }
    __syncthreads();

    bf16x8 wreg[48];
#pragma unroll
    for (int k = 0; k < 6; ++k)
#pragma unroll
        for (int j = 0; j < 8; ++j)
            wreg[k * 8 + j] = wpA[(k * 64 + wid * 8 + j) * 64 + lane];

    float b1v[2][4];
#pragma unroll
    for (int hf = 0; hf < 2; ++hf)
#pragma unroll
        for (int g = 0; g < 4; ++g)
            b1v[hf][g] = b1[g * 256 + wid * 32 + hf * 16 + lc];

    const f32x4 zf = {0.f, 0.f, 0.f, 0.f};
    const bf16x8* wldsv = (const bf16x8*)wlds;

    for (int t = t0; t < t1; ++t) {
        const int rb_ = t & 1;
        const bf16* hr = h1s[rb_];
        bf16* hw = h1s[rb_ ^ 1];

        bf16x8 ax;
        for (int e = 0; e < 8; ++e) ax[e] = (bf16)0.0f;
        if (lg == 0) ax = *(const bf16x8*)&embl[(int)toks8[(lc & 7) * T_SZ + t] * 8];

#pragma unroll
        for (int hf = 0; hf < 2; ++hf) {
            f32x4 a4[4];
#pragma unroll
            for (int g = 0; g < 4; ++g) a4[g] = zf;
#pragma unroll
            for (int g = 0; g < 4; ++g) {
                bf16x8 xw = w1xg[(wid * 8 + hf * 4 + g) * 64 + lane];
                a4[g] = __builtin_amdgcn_mfma_f32_16x16x32_bf16(ax, xw, a4[g], 0, 0, 0);
            }
#pragma unroll
            for (int k = 0; k < 6; ++k) {
                bf16x8 afr = AFRAG(hr, k);
#pragma unroll
                for (int g = 0; g < 4; ++g)
                    a4[g] = __builtin_amdgcn_mfma_f32_16x16x32_bf16(afr, wreg[k * 8 + hf * 4 + g], a4[g], 0, 0, 0);
            }
#pragma unroll
            for (int k = 6; k < 8; ++k) {
                bf16x8 afr = AFRAG(hr, k);
#pragma unroll
                for (int g = 0; g < 4; ++g) {
                    bf16x8 w = wldsv[((k - 6) * 64 + wid * 8 + hf * 4 + g) * 64 + lane];
                    a4[g] = __builtin_amdgcn_mfma_f32_16x16x32_bf16(afr, w, a4[g], 0, 0, 0);
                }
            }
            if (lg < 2) {
                const int hcol = wid * 32 + hf * 16 + lc;
#pragma unroll
                for (int r = 0; r < 4; ++r) {
                    const int row = lg * 4 + r;
                    float gi = a4[0][r] + b1v[hf][0];
                    float gj = a4[1][r] + b1v[hf][1];
                    float gf = a4[2][r] + b1v[hf][2];
                    float go = a4[3][r] + b1v[hf][3];
                    float cn = c1[hf][r] * sigf(gf + 1.0f) + sigf(gi) * tanhf2(gj);
                    float h  = tanhf2(cn) * sigf(go);
                    c1[hf][r] = cn;
                    unsigned short hb = f2bf(h);
                    hw[HSWZ(row, hcol)] = *(bf16*)&hb;
                    h1c[((size_t)(b0 + row) * TC + (t - t0)) * 256 + hcol] = hb;
                }
            }
        }
        __syncthreads();
    }
    // persist c1 state for next chunk
    if (t1 < T_SZ && lg < 2) {
#pragma unroll
        for (int hf = 0; hf < 2; ++hf)
#pragma unroll
            for (int r = 0; r < 4; ++r)
                c1g[(size_t)(b0 + lg * 4 + r) * 256 + wid * 32 + hf * 16 + lc] = c1[hf][r];
    }
}

// ===================== kernel G: gxc = h1c @ W2x + b2 (time chunk) =====================
// gxc[bblk][dt][nt][lc][rb] bf16 ; M-tile = 8 rows x 2 t  (m = row*2+dtp)
__global__ __launch_bounds__(NTHR, 2)
void gx_gemm(const unsigned short* __restrict__ h1c, const bf16x8* __restrict__ wpG,
             const float* __restrict__ b2, unsigned short* __restrict__ gxc, int TC)
{
    __shared__ __align__(16) bf16 wlds[2 * 4096 * 8];     // 128 KB
    __shared__ __align__(16) bf16 hbuf[16 * 256];         // 8 KB

    const int tid  = threadIdx.x;
    const int lane = tid & 63;
    const int wid  = tid >> 6;
    const int lc   = lane & 15;
    const int lg   = lane >> 4;
    const int bblk = blockIdx.x;

    {
        bf16x8* wv = (bf16x8*)wlds;
        for (int i = tid; i < 2 * 4096; i += NTHR) wv[i] = wpG[6 * 4096 + i];
    }
    bf16x8 wreg[48];
#pragma unroll
    for (int k = 0; k < 6; ++k)
#pragma unroll
        for (int j = 0; j < 8; ++j)
            wreg[k * 8 + j] = wpG[(k * 64 + wid * 8 + j) * 64 + lane];

    float b2v[8];
#pragma unroll
    for (int j = 0; j < 8; ++j)
        b2v[j] = b2[(j & 3) * 256 + wid * 32 + ((j >> 2) & 1) * 16 + lc];

    const f32x4 zf = {0.f, 0.f, 0.f, 0.f};
    const bf16x8* wldsv = (const bf16x8*)wlds;
    const int m    = tid >> 5;
    const int col0 = (tid & 31) * 8;
    const int np   = TC >> 1;

    bf16x8 sreg = *(const bf16x8*)&h1c[((size_t)(bblk * 8 + (m >> 1)) * TC + (m & 1)) * 256 + col0];

    for (int tt = 0; tt < np; ++tt) {
        __syncthreads();
        *(bf16x8*)&hbuf[m * 256 + ((((tid & 31) + 2 * m) & 31) << 3)] = sreg;
        __syncthreads();
        if (tt + 1 < np)
            sreg = *(const bf16x8*)&h1c[((size_t)(bblk * 8 + (m >> 1)) * TC + (tt + 1) * 2 + (m & 1)) * 256 + col0];

        f32x4 acc[8];
#pragma unroll
        for (int j = 0; j < 8; ++j) acc[j] = zf;
#pragma unroll
        for (int k = 0; k < 8; ++k) {
            bf16x8 afr = AFRAG(hbuf, k);
#pragma unroll
            for (int j = 0; j < 8; ++j) {
                bf16x8 w = (k < 6) ? wreg[k * 8 + j]
                                   : wldsv[((k - 6) * 64 + wid * 8 + j) * 64 + lane];
                acc[j] = __builtin_amdgcn_mfma_f32_16x16x32_bf16(afr, w, acc[j], 0, 0, 0);
            }
        }
#pragma unroll
        for (int j = 0; j < 8; ++j) {
            const int nt = wid * 8 + j;
#pragma unroll
            for (int r = 0; r < 4; ++r) {
                size_t addr = ((((size_t)bblk * TC + tt * 2 + (r & 1)) * 64 + nt) * 16 + lc) * 8
                              + 2 * lg + (r >> 1);
                gxc[addr] = f2bf(acc[j][r] + b2v[j]);
            }
        }
    }
}

// ===================== kernel B: layer-2 recurrence (+ loss on final chunk) =====================
__global__ __launch_bounds__(NTHR, 2)
void lstm_l2(const bf16x8* __restrict__ wpB, const unsigned short* __restrict__ gxc,
             const int* __restrict__ labels,
             const float* __restrict__ Wd, const float* __restrict__ bd,
             float* __restrict__ out, float* __restrict__ c2g,
             unsigned short* __restrict__ h2p, int t0, int TC)
{
    __shared__ __align__(16) bf16 wlds[2 * 4096 * 8];     // 128 KB
    __shared__ __align__(16) bf16 h2s[2][16 * 256];       // 16 KB
    __shared__ float logitb[8][VOCABN + 1];
    __shared__ float lossb[8];

    const int tid  = threadIdx.x;
    const int lane = tid & 63;
    const int wid  = tid >> 6;
    const int lc   = lane & 15;
    const int lg   = lane >> 4;
    const int bblk = blockIdx.x;
    const int b0   = bblk * 8;
    const int t1   = t0 + TC;

    for (int i = tid; i < 2 * 16 * 256; i += NTHR) h2s[0][i] = (bf16)0.0f;
    {
        bf16x8* wv = (bf16x8*)wlds;
        for (int i = tid; i < 2 * 4096; i += NTHR) wv[i] = wpB[6 * 4096 + i];
    }
    float c2[2][4] = {{0.f,0.f,0.f,0.f},{0.f,0.f,0.f,0.f}};
    if (t0 > 0) {
        __syncthreads();
        for (int i = tid; i < 256; i += NTHR) {
            int row = i >> 5, col0 = (i & 31) << 3;
            bf16x8 v = *(const bf16x8*)&h2p[(size_t)(b0 + row) * 256 + col0];
            *(bf16x8*)&h2s[0][HSWZ(row, col0)] = v;
        }
        if (lg < 2) {
#pragma unroll
            for (int hf = 0; hf < 2; ++hf)
#pragma unroll
                for (int r = 0; r < 4; ++r)
                    c2[hf][r] = c2g[(size_t)(b0 + lg * 4 + r) * 256 + wid * 32 + hf * 16 + lc];
        }
    }
    __syncthreads();

    bf16x8 wreg[48];
#pragma unroll
    for (int k = 0; k < 6; ++k)
#pragma unroll
        for (int j = 0; j < 8; ++j)
            wreg[k * 8 + j] = wpB[(k * 64 + wid * 8 + j) * 64 + lane];

    const f32x4 zf = {0.f, 0.f, 0.f, 0.f};
    const bf16x8* wldsv = (const bf16x8*)wlds;

    for (int t = t0; t < t1; ++t) {
        const int rb_ = t & 1;
        const bf16* hr = h2s[rb_];
        bf16* hw = h2s[rb_ ^ 1];

        u16x4 gxv[2][4];
        if (lg < 2) {
#pragma unroll
            for (int hf = 0; hf < 2; ++hf)
#pragma unroll
                for (int g = 0; g < 4; ++g) {
                    const int nt = wid * 8 + hf * 4 + g;
                    size_t addr = ((((size_t)bblk * TC + (t - t0)) * 64 + nt) * 16 + lc) * 8 + 4 * lg;
                    gxv[hf][g] = *(const u16x4*)(gxc + addr);
                }
        }

#pragma unroll
        for (int hf = 0; hf < 2; ++hf) {
            f32x4 a4[4];
#pragma unroll
            for (int g = 0; g < 4; ++g) a4[g] = zf;
#pragma unroll
            for (int k = 0; k < 6; ++k) {
                bf16x8 afr = AFRAG(hr, k);
#pragma unroll
                for (int g = 0; g < 4; ++g)
                    a4[g] = __builtin_amdgcn_mfma_f32_16x16x32_bf16(afr, wreg[k * 8 + hf * 4 + g], a4[g], 0, 0, 0);
            }
#pragma unroll
            for (int k = 6; k < 8; ++k) {
                bf16x8 afr = AFRAG(hr, k);
#pragma unroll
                for (int g = 0; g < 4; ++g) {
                    bf16x8 w = wldsv[((k - 6) * 64 + wid * 8 + hf * 4 + g) * 64 + lane];
                    a4[g] = __builtin_amdgcn_mfma_f32_16x16x32_bf16(afr, w, a4[g], 0, 0, 0);
                }
            }
            if (lg < 2) {
                const int hcol = wid * 32 + hf * 16 + lc;
#pragma unroll
                for (int r = 0; r < 4; ++r) {
                    const int row = lg * 4 + r;
                    float gi = a4[0][r] + bf2f(gxv[hf][0][r]);
                    float gj = a4[1][r] + bf2f(gxv[hf][1][r]);
                    float gf = a4[2][r] + bf2f(gxv[hf][2][r]);
                    float go = a4[3][r] + bf2f(gxv[hf][3][r]);
                    float cn = c2[hf][r] * sigf(gf + 1.0f) + sigf(gi) * tanhf2(gj);
                    float h  = tanhf2(cn) * sigf(go);
                    c2[hf][r] = cn;
                    unsigned short hb = f2bf(h);
                    hw[HSWZ(row, hcol)] = *(bf16*)&hb;
                }
            }
        }
        __syncthreads();
    }

    if (t1 < T_SZ) {
        // persist state (final h2 of this chunk is in h2s[0] since t1 even)
        if (lg < 2) {
#pragma unroll
            for (int hf = 0; hf < 2; ++hf)
#pragma unroll
                for (int r = 0; r < 4; ++r)
                    c2g[(size_t)(b0 + lg * 4 + r) * 256 + wid * 32 + hf * 16 + lc] = c2[hf][r];
        }
        for (int i = tid; i < 256; i += NTHR) {
            int row = i >> 5, col0 = (i & 31) << 3;
            bf16x8 v = *(const bf16x8*)&h2s[0][HSWZ(row, col0)];
            *(bf16x8*)&h2p[(size_t)(b0 + row) * 256 + col0] = v;
        }
        return;
    }

    // ---- loss epilogue (final chunk): final h2 in h2s[0] ----
    const bf16* h2fin = h2s[0];
    for (int pp = tid; pp < 8 * VOCABN; pp += NTHR) {
        int row = pp / VOCABN, v = pp - row * VOCABN;
        float s = bd[v];
        for (int k = 0; k < HID; ++k)
            s += (float)h2fin[HSWZ(row, k)] * Wd[k * VOCABN + v];
        logitb[row][v] = s;
    }
    __syncthreads();
    if (tid < 8) {
        float mx = -1e30f;
        for (int v = 0; v < VOCABN; ++v) mx = fmaxf(mx, logitb[tid][v]);
        float s = 0.f;
        for (int v = 0; v < VOCABN; ++v) s += __expf(logitb[tid][v] - mx);
        int lab = labels[b0 + tid];
        lossb[tid] = mx + __logf(s) - logitb[tid][lab];
    }
    __syncthreads();
    if (tid == 0) {
        float s = 0.f;
#pragma unroll
        for (int r = 0; r < 8; ++r) s += lossb[r];
        atomicAdd(out, s * (1.0f / (float)B_SZ));
    }
}

// ===================== R5 fallback (verbatim, passed @5.16ms) =====================
#define NCH_R5 24
#define CHE_R5 32768
#define TILE_R5 16
#define NBLK_R5 (B_SZ / TILE_R5)

__global__ void prep_w_r5(const float* __restrict__ W1, const float* __restrict__ W2,
                          unsigned short* __restrict__ wp) {
    int idx = blockIdx.x * blockDim.x + threadIdx.x;
    if (idx >= 25 * 64 * 64) return;
    int lane = idx & 63, nt = (idx >> 6) & 63, k = idx >> 12;
    int scol = (nt << 4) + (lane & 15);
    int lg = lane >> 4;
#pragma unroll
    for (int e = 0; e < 8; ++e) {
        float val;
        if (k < 8)       val = W1[(EMBN + k * 32 + lg * 8 + e) * G4 + scol];
        else if (k < 24) val = W2[((k - 8) * 32 + lg * 8 + e) * G4 + scol];
        else             val = (lg == 0) ? W1[e * G4 + scol] : 0.0f;
        wp[idx * 8 + e] = f2bf(val);
    }
}

#define WAITVM_R5(N) do { asm volatile("s_waitcnt vmcnt(" #N ")" ::: "memory"); \
                       __builtin_amdgcn_sched_barrier(0); } while (0)
#define WAITLG_R5    do { asm volatile("s_waitcnt lgkmcnt(0)" ::: "memory");    \
                       __builtin_amdgcn_sched_barrier(0); } while (0)
#define BAR_R5       do { __builtin_amdgcn_s_barrier();                         \
                       __builtin_amdgcn_sched_barrier(0); } while (0)

#define STAGE_R5(kk, bb) do {                                                   \
    const bf16* gs_ = wp + (size_t)(kk) * CHE_R5;                               \
    _Pragma("unroll")                                                           \
    for (int j_ = 0; j_ < 8; ++j_) {                                            \
        const int f_ = j_ * 512 + wid * 64;                                     \
        __builtin_amdgcn_global_load_lds(                                       \
            (const __attribute__((address_space(1))) void*)(gs_ + (size_t)(f_ + lane) * 8), \
            (__attribute__((address_space(3))) void*)(&wbuf[bb][0] + (size_t)f_ * 8),       \
            16, 0, 0);                                                          \
    }                                                                           \
} while (0)

#define CHUNK_R5(c, HSRC, KIDX, EXTRA) do {                                     \
    WAITVM_R5(8); BAR_R5;                                                       \
    {                                                                           \
        const bf16* wb_ = wbuf[(c) & 1];                                        \
        bf16x8 afr_ = AFRAG(HSRC, KIDX);                                        \
        _Pragma("unroll")                                                       \
        for (int j_ = 0; j_ < 8; ++j_) {                                        \
            const int nt_ = (j_ >> 1) * 16 + 2 * wid + (j_ & 1);                \
            bf16x8 w_ = *(const bf16x8*)&wb_[(nt_ * 64 + lane) * 8];            \
            acc[j_ >> 1][j_ & 1] = __builtin_amdgcn_mfma_f32_16x16x32_bf16(     \
                afr_, w_, acc[j_ >> 1][j_ & 1], 0, 0, 0);                       \
        }                                                                       \
        EXTRA;                                                                  \
    }                                                                           \
    WAITLG_R5; BAR_R5;                                                          \
    STAGE_R5(((c) + 2) % NCH_R5, ((c) + 2) & 1);                                \
} while (0)

#define XMFMA_R5 do {                                                           \
    const int tok_ = toks[lc * T_SZ + t];                                       \
    bf16x8 ax_;                                                                 \
    _Pragma("unroll") for (int e_ = 0; e_ < 8; ++e_) ax_[e_] = (bf16)0.0f;      \
    if (lg == 0) ax_ = *(const bf16x8*)&embL[tok_ * 8];                         \
    _Pragma("unroll")                                                           \
    for (int j_ = 0; j_ < 8; ++j_)                                              \
        acc[j_ >> 1][j_ & 1] = __builtin_amdgcn_mfma_f32_16x16x32_bf16(         \
            ax_, w1x[j_], acc[j_ >> 1][j_ & 1], 0, 0, 0);                       \
} while (0)

#define ACCZ_R5() do { _Pragma("unroll") for (int g_ = 0; g_ < 4; ++g_) {       \
    acc[g_][0] = zf; acc[g_][1] = zf; } } while (0)

__global__ __launch_bounds__(NTHR, 2)
void lstm_fused_r5(const int* __restrict__ feat, const int* __restrict__ labels,
                const bf16* __restrict__ wp,
                const float* __restrict__ b1, const float* __restrict__ b2,
                const float* __restrict__ emb,
                const float* __restrict__ Wd, const float* __restrict__ bd,
                float* __restrict__ out)
{
    __shared__ __align__(16) bf16  wbuf[2][CHE_R5];
    __shared__ __align__(16) bf16  h1s[TILE_R5 * 256];
    __shared__ __align__(16) bf16  h2s[TILE_R5 * 256];
    __shared__ __align__(16) bf16  embL[VOCABN * 8];
    __shared__ int   toks[TILE_R5 * T_SZ];
    __shared__ float logitb[TILE_R5][VOCABN + 1];
    __shared__ float lossb[TILE_R5];

    const int tid  = threadIdx.x;
    const int lane = tid & 63;
    const int wid  = tid >> 6;
    const int lc   = lane & 15;
    const int lg   = lane >> 4;
    const int b0   = blockIdx.x * TILE_R5;

    for (int i = tid; i < TILE_R5 * 256; i += NTHR) { h1s[i] = (bf16)0.0f; h2s[i] = (bf16)0.0f; }
    for (int i = tid; i < TILE_R5 * T_SZ; i += NTHR) {
        int r = i / T_SZ, t = i - r * T_SZ;
        toks[r * T_SZ + t] = feat[(b0 + r) * T_SZ + t];
    }
    for (int i = tid; i < VOCABN * 8; i += NTHR) ((unsigned short*)embL)[i] = f2bf(emb[i]);
    __syncthreads();

    bf16x8 w1x[8];
#pragma unroll
    for (int j = 0; j < 8; ++j) {
        const int nt = (j >> 1) * 16 + 2 * wid + (j & 1);
        w1x[j] = *(const bf16x8*)&wp[((size_t)24 * 64 * 64 + nt * 64 + lane) * 8];
    }
    float b1v[4][2], b2v[4][2];
#pragma unroll
    for (int g = 0; g < 4; ++g)
#pragma unroll
        for (int d = 0; d < 2; ++d) {
            b1v[g][d] = b1[g * 256 + (2 * wid + d) * 16 + lc];
            b2v[g][d] = b2[g * 256 + (2 * wid + d) * 16 + lc];
        }

    const f32x4 zf = {0.f, 0.f, 0.f, 0.f};
    f32x4 acc[4][2];
    float c1s[2][4] = {{0.f,0.f,0.f,0.f},{0.f,0.f,0.f,0.f}};
    float c2s[2][4] = {{0.f,0.f,0.f,0.f},{0.f,0.f,0.f,0.f}};

    STAGE_R5(0, 0);
    STAGE_R5(1, 1);

    for (int t = 0; t < T_SZ; ++t) {
        ACCZ_R5();
        CHUNK_R5(0, h1s, 0, XMFMA_R5);
        CHUNK_R5(1, h1s, 1, );
        CHUNK_R5(2, h1s, 2, );
        CHUNK_R5(3, h1s, 3, );
        CHUNK_R5(4, h1s, 4, );
        CHUNK_R5(5, h1s, 5, );
        CHUNK_R5(6, h1s, 6, );
        CHUNK_R5(7, h1s, 7, );
#pragma unroll
        for (int d = 0; d < 2; ++d) {
            const int hcol = (2 * wid + d) * 16 + lc;
#pragma unroll
            for (int rr = 0; rr < 4; ++rr) {
                const int row = lg * 4 + rr;
                float gi = acc[0][d][rr] + b1v[0][d];
                float gj = acc[1][d][rr] + b1v[1][d];
                float gf = acc[2][d][rr] + b1v[2][d];
                float go = acc[3][d][rr] + b1v[3][d];
                float cn = c1s[d][rr] * sigf(gf + 1.0f) + sigf(gi) * tanhf2(gj);
                float h  = tanhf2(cn) * sigf(go);
                c1s[d][rr] = cn;
                h1s[HSWZ(row, hcol)] = (bf16)h;
            }
        }
        ACCZ_R5();
        CHUNK_R5(8,  h1s, 0, );
        CHUNK_R5(9,  h1s, 1, );
        CHUNK_R5(10, h1s, 2, );
        CHUNK_R5(11, h1s, 3, );
        CHUNK_R5(12, h1s, 4, );
        CHUNK_R5(13, h1s, 5, );
        CHUNK_R5(14, h1s, 6, );
        CHUNK_R5(15, h1s, 7, );
        CHUNK_R5(16, h2s, 0, );
        CHUNK_R5(17, h2s, 1, );
        CHUNK_R5(18, h2s, 2, );
        CHUNK_R5(19, h2s, 3, );
        CHUNK_R5(20, h2s, 4, );
        CHUNK_R5(21, h2s, 5, );
        CHUNK_R5(22, h2s, 6, );
        CHUNK_R5(23, h2s, 7, );
#pragma unroll
        for (int d = 0; d < 2; ++d) {
            const int hcol = (2 * wid + d) * 16 + lc;
#pragma unroll
            for (int rr = 0; rr < 4; ++rr) {
                const int row = lg * 4 + rr;
                float gi = acc[0][d][rr] + b2v[0][d];
                float gj = acc[1][d][rr] + b2v[1][d];
                float gf = acc[2][d][rr] + b2v[2][d];
                float go = acc[3][d][rr] + b2v[3][d];
                float cn = c2s[d][rr] * sigf(gf + 1.0f) + sigf(gi) * tanhf2(gj);
                float h  = tanhf2(cn) * sigf(go);
                c2s[d][rr] = cn;
                h2s[HSWZ(row, hcol)] = (bf16)h;
            }
        }
    }
    __syncthreads();

    for (int pp = tid; pp < TILE_R5 * VOCABN; pp += NTHR) {
        int row = pp / VOCABN, v = pp - row * VOCABN;
        float s = bd[v];
        for (int k = 0; k < HID; ++k)
            s += (float)h2s[HSWZ(row, k)] * Wd[k * VOCABN + v];
        logitb[row][v] = s;
    }
    __syncthreads();
    if (tid < TILE_R5) {
        const int row = tid;
        float m = -1e30f;
        for (int v = 0; v < VOCABN; ++v) m = fmaxf(m, logitb[row][v]);
        float s = 0.f;
        for (int v = 0; v < VOCABN; ++v) s += __expf(logitb[row][v] - m);
        int lab = labels[b0 + row];
        lossb[row] = m + __logf(s) - logitb[row][lab];
    }
    __syncthreads();
    if (tid == 0) {
        float s = 0.f;
#pragma unroll
        for (int rr = 0; rr < TILE_R5; ++rr) s += lossb[rr];
        atomicAdd(out, s * (1.0f / (float)B_SZ));
    }
}

// ===================== launch =====================
extern "C" void kernel_launch(void* const* d_in, const int* in_sizes, int n_in,
                              void* d_out, int out_size, void* d_ws, size_t ws_size,
                              hipStream_t stream)
{
    (void)in_sizes; (void)n_in; (void)out_size;
    const int*   feat   = (const int*)d_in[0];
    const int*   labels = (const int*)d_in[1];
    const float* emb    = (const float*)d_in[2];
    const float* W1     = (const float*)d_in[3];
    const float* b1     = (const float*)d_in[4];
    const float* W2     = (const float*)d_in[5];
    const float* b2     = (const float*)d_in[6];
    const float* Wd     = (const float*)d_in[7];
    const float* bd     = (const float*)d_in[8];
    float* out = (float*)d_out;
    char* ws = (char*)d_ws;

    (void)hipMemsetAsync(d_out, 0, sizeof(float), stream);

    // pick largest even time-chunk that fits
    int TC = 0;
    {
        const int tcs[7] = {40, 20, 16, 10, 8, 4, 2};
        for (int i = 0; i < 7; ++i)
            if (FIXED_WS + (size_t)tcs[i] * PER_TC <= ws_size) { TC = tcs[i]; break; }
    }

    if (TC > 0) {
        unsigned short* wpA  = (unsigned short*)(ws + WPA_OFF);
        unsigned short* wpG  = (unsigned short*)(ws + WPG_OFF);
        unsigned short* wpB  = (unsigned short*)(ws + WPB_OFF);
        unsigned short* w1xg = (unsigned short*)(ws + W1X_OFF);
        float*          c1g  = (float*)(ws + C1G_OFF);
        float*          c2g  = (float*)(ws + C2G_OFF);
        unsigned short* h2p  = (unsigned short*)(ws + H2P_OFF);
        unsigned short* h1c  = (unsigned short*)(ws + H1C_OFF);
        unsigned short* gxc  = (unsigned short*)(ws + H1C_OFF + (size_t)TC * 1048576ull);

        prep_all<<<(3 * 8 * 64 * 64 + 64 * 64 + 255) / 256, 256, 0, stream>>>(
            W1, W2, wpA, wpG, wpB, w1xg);
        for (int t0 = 0; t0 < T_SZ; t0 += TC) {
            lstm_l1<<<256, NTHR, 0, stream>>>(feat, (const bf16x8*)wpA, (const bf16x8*)w1xg,
                                              emb, b1, h1c, c1g, t0, TC);
            gx_gemm<<<256, NTHR, 0, stream>>>(h1c, (const bf16x8*)wpG, b2, gxc, TC);
            lstm_l2<<<256, NTHR, 0, stream>>>((const bf16x8*)wpB, gxc, labels, Wd, bd,
                                              out, c2g, h2p, t0, TC);
        }
    } else {
        bf16* wp = (bf16*)d_ws;
        prep_w_r5<<<(25 * 64 * 64 + 255) / 256, 256, 0, stream>>>(W1, W2, (unsigned short*)wp);
        lstm_fused_r5<<<NBLK_R5, NTHR, 0, stream>>>(feat, labels, wp, b1, b2, emb, Wd, bd, out);
    }
}